// Round 1
// baseline (2074.390 us; speedup 1.0000x reference)
//
#include <hip/hip_runtime.h>
#include <math.h>

#define SEQ   2048
#define BATCH 8
#define EMB   1024
#define HEADS 8
#define PROJ  64
#define CHAINS (BATCH * HEADS)   // 64 independent GRU chains

// ---------------------------------------------------------------------------
// Tiled f32 GEMM: C[M,N] = A[M,K] * B[K,N], all row-major, dims divisible by
// tile sizes (M%128==0, N%64==0, K%16==0). 256 threads, 8x4 microtile.
// ---------------------------------------------------------------------------
template <int BM, int BN, int BK>
__global__ __launch_bounds__(256)
void gemm_f32(const float* __restrict__ A, const float* __restrict__ B,
              float* __restrict__ C, int M, int N, int K) {
    __shared__ float As[BK][BM + 4];  // transposed store, +4 pad (keeps 16B align)
    __shared__ float Bs[BK][BN];

    const int t    = threadIdx.x;
    const int brow = blockIdx.x * BM;
    const int bcol = blockIdx.y * BN;

    // microtile: 8 rows x 4 cols per thread
    const int tm = (t / 16) * 8;  // 0..120
    const int tn = (t % 16) * 4;  // 0..60

    // A staging: 128x16 tile, 2 float4 per thread
    const int ar = t / 4;          // 0..63
    const int ac = (t % 4) * 4;    // 0,4,8,12
    // B staging: 16x64 tile, 1 float4 per thread
    const int br = t / 16;         // 0..15
    const int bc = (t % 16) * 4;   // 0..60

    float acc[8][4];
#pragma unroll
    for (int i = 0; i < 8; ++i)
#pragma unroll
        for (int j = 0; j < 4; ++j) acc[i][j] = 0.f;

    const int ktiles = K / BK;
    for (int kt = 0; kt < ktiles; ++kt) {
        const int k0 = kt * BK;
        const float4 a0 = *(const float4*)&A[(size_t)(brow + ar) * K + k0 + ac];
        const float4 a1 = *(const float4*)&A[(size_t)(brow + ar + 64) * K + k0 + ac];
        const float4 b0 = *(const float4*)&B[(size_t)(k0 + br) * N + bcol + bc];

        __syncthreads();  // previous tile fully consumed
        As[ac + 0][ar] = a0.x;  As[ac + 1][ar] = a0.y;
        As[ac + 2][ar] = a0.z;  As[ac + 3][ar] = a0.w;
        As[ac + 0][ar + 64] = a1.x;  As[ac + 1][ar + 64] = a1.y;
        As[ac + 2][ar + 64] = a1.z;  As[ac + 3][ar + 64] = a1.w;
        *(float4*)&Bs[br][bc] = b0;
        __syncthreads();  // tile staged

#pragma unroll
        for (int kk = 0; kk < BK; ++kk) {
            const float4 av0 = *(const float4*)&As[kk][tm];
            const float4 av1 = *(const float4*)&As[kk][tm + 4];
            const float4 bv  = *(const float4*)&Bs[kk][tn];
            const float a[8] = {av0.x, av0.y, av0.z, av0.w,
                                av1.x, av1.y, av1.z, av1.w};
            const float b[4] = {bv.x, bv.y, bv.z, bv.w};
#pragma unroll
            for (int i = 0; i < 8; ++i)
#pragma unroll
                for (int j = 0; j < 4; ++j)
                    acc[i][j] = fmaf(a[i], b[j], acc[i][j]);
        }
    }

#pragma unroll
    for (int i = 0; i < 8; ++i) {
        float4 v = make_float4(acc[i][0], acc[i][1], acc[i][2], acc[i][3]);
        *(float4*)&C[(size_t)(brow + tm + i) * N + bcol + tn] = v;
    }
}

// ---------------------------------------------------------------------------
// GRU scan. One block per (batch,head) chain; 192 threads = 3 waves.
// Thread t owns gate row t of w_ih and w_hh (64+64 floats in VGPRs).
// xp buffer [SEQ, CHAINS, PROJ] is consumed and overwritten in place with ys.
//   gates: t in [0,64)=r, [64,128)=z, [128,192)=n
//   r = sigmoid(ir+hr); z = sigmoid(iz+hz); n = tanh(inn + r*(hn + b_n));
//   h' = n + z*(h - n)
// ---------------------------------------------------------------------------
__global__ __launch_bounds__(192)
void gru_scan(const float* __restrict__ w_ih, const float* __restrict__ w_hh,
              const float* __restrict__ b_ih, const float* __restrict__ b_n,
              float* __restrict__ xp) {
    const int c = blockIdx.x;   // chain = b*HEADS + h
    const int t = threadIdx.x;  // 0..191

    __shared__ float h_s[PROJ];
    __shared__ float xt_s[2][PROJ];
    __shared__ float rz_s[2 * PROJ];
    __shared__ float inn_s[PROJ];
    __shared__ float hn_s[PROJ];

    // weights into registers (fully unrolled -> stays in VGPRs)
    float wih[64], whh[64];
#pragma unroll
    for (int q = 0; q < 16; ++q) {
        const float4 wi = *(const float4*)&w_ih[(size_t)t * 64 + q * 4];
        const float4 wh = *(const float4*)&w_hh[(size_t)t * 64 + q * 4];
        wih[q * 4 + 0] = wi.x; wih[q * 4 + 1] = wi.y;
        wih[q * 4 + 2] = wi.z; wih[q * 4 + 3] = wi.w;
        whh[q * 4 + 0] = wh.x; whh[q * 4 + 1] = wh.y;
        whh[q * 4 + 2] = wh.z; whh[q * 4 + 3] = wh.w;
    }
    const float bih_t = b_ih[t];
    const float bn_p  = (t < PROJ) ? b_n[t] : 0.f;

    if (t < PROJ) {
        h_s[t] = 0.f;
        xt_s[0][t] = xp[(size_t)c * PROJ + t];  // x_t for s=0
    }
    __syncthreads();

    float h_reg = 0.f;  // valid for t < 64: mirrors h_s[t]

    for (int s = 0; s < SEQ; ++s) {
        // prefetch next step's x_t (wave 0 only) — issued before the dot work
        float nxt = 0.f;
        if (t < PROJ && s + 1 < SEQ)
            nxt = xp[((size_t)(s + 1) * CHAINS + c) * PROJ + t];

        // ig = b_ih[t] + dot(x_t, w_ih[t,:]);  hg = dot(h, w_hh[t,:])
        const float4* xs4 = (const float4*)xt_s[s & 1];
        const float4* hs4 = (const float4*)h_s;
        float ig0 = bih_t, ig1 = 0.f, ig2 = 0.f, ig3 = 0.f;
        float hg0 = 0.f,   hg1 = 0.f, hg2 = 0.f, hg3 = 0.f;
#pragma unroll
        for (int q = 0; q < 16; ++q) {
            const float4 xv = xs4[q];
            const float4 hv = hs4[q];
            ig0 = fmaf(xv.x, wih[q * 4 + 0], ig0);
            ig1 = fmaf(xv.y, wih[q * 4 + 1], ig1);
            ig2 = fmaf(xv.z, wih[q * 4 + 2], ig2);
            ig3 = fmaf(xv.w, wih[q * 4 + 3], ig3);
            hg0 = fmaf(hv.x, whh[q * 4 + 0], hg0);
            hg1 = fmaf(hv.y, whh[q * 4 + 1], hg1);
            hg2 = fmaf(hv.z, whh[q * 4 + 2], hg2);
            hg3 = fmaf(hv.w, whh[q * 4 + 3], hg3);
        }
        const float ig = (ig0 + ig1) + (ig2 + ig3);
        const float hg = (hg0 + hg1) + (hg2 + hg3);

        if (t < 2 * PROJ) {
            rz_s[t] = ig + hg;          // r and z pre-activations
        } else {
            inn_s[t - 2 * PROJ] = ig;   // includes b_ih n-slice
            hn_s[t - 2 * PROJ]  = hg;   // bias b_n added below
        }
        __syncthreads();

        if (t < PROJ) {
            const float r = 1.f / (1.f + __expf(-rz_s[t]));
            const float z = 1.f / (1.f + __expf(-rz_s[PROJ + t]));
            const float n = tanhf(inn_s[t] + r * (hn_s[t] + bn_p));
            const float hnew = n + z * (h_reg - n);
            h_reg = hnew;
            h_s[t] = hnew;
            xp[((size_t)s * CHAINS + c) * PROJ + t] = hnew;  // ys, in place
            if (s + 1 < SEQ) xt_s[(s + 1) & 1][t] = nxt;
        }
        __syncthreads();
    }
}

// ---------------------------------------------------------------------------
extern "C" void kernel_launch(void* const* d_in, const int* in_sizes, int n_in,
                              void* d_out, int out_size, void* d_ws, size_t ws_size,
                              hipStream_t stream) {
    const float* x     = (const float*)d_in[0];  // [S,B,E]
    const float* w_in  = (const float*)d_in[1];  // [E,H,P] -> [1024,512]
    const float* w_ih  = (const float*)d_in[2];  // [192,64]
    const float* w_hh  = (const float*)d_in[3];  // [192,64]
    const float* b_ih  = (const float*)d_in[4];  // [192]
    const float* b_n   = (const float*)d_in[5];  // [64]
    const float* w_out = (const float*)d_in[6];  // [H,P,E] -> [512,1024]
    float* out = (float*)d_out;                  // [S,B,E]
    float* xp  = (float*)d_ws;                   // [S,B,H,P] = 33.5 MB, reused as ys

    const int M = SEQ * BATCH;          // 16384
    const int N1 = HEADS * PROJ;        // 512
    const int K1 = EMB;                 // 1024

    // 1) xp = x @ w_in
    dim3 g1(M / 128, N1 / 64);
    gemm_f32<128, 64, 16><<<g1, 256, 0, stream>>>(x, w_in, xp, M, N1, K1);

    // 2) GRU scan over S (in-place xp -> ys)
    gru_scan<<<CHAINS, 192, 0, stream>>>(w_ih, w_hh, b_ih, b_n, xp);

    // 3) out = ys @ w_out
    dim3 g3(M / 128, EMB / 64);
    gemm_f32<128, 64, 16><<<g3, 256, 0, stream>>>(xp, w_out, out, M, EMB, N1);
}

// Round 2
// 1610.367 us; speedup vs baseline: 1.2881x; 1.2881x over previous
//
#include <hip/hip_runtime.h>
#include <math.h>

#define SEQ    2048
#define BATCH  8
#define EMB    1024
#define HEADS  8
#define PROJ   64
#define CHAINS (BATCH * HEADS)   // 64 independent GRU chains
#define GATES  (3 * PROJ)        // 192

typedef float f2 __attribute__((ext_vector_type(2)));

// packed f32 FMA: acc.xy += a.xy * b.xy  (CDNA2+ V_PK_FMA_F32)
#define PKFMA(acc, a, b) asm("v_pk_fma_f32 %0, %1, %2, %0" : "+v"(acc) : "v"(a), "v"(b))

static __device__ __forceinline__ float bf2f(unsigned short u) {
    union { unsigned int i; float f; } c; c.i = ((unsigned int)u) << 16; return c.f;
}
static __device__ __forceinline__ unsigned short f2bf(float f) {
    union { float f; unsigned int i; } c; c.f = f;
    unsigned int u = c.i;
    u += 0x7fffu + ((u >> 16) & 1u);   // round-to-nearest-even
    return (unsigned short)(u >> 16);
}

// ---------------------------------------------------------------------------
// Tiled f32 GEMM: C[M,N] = A[M,K]*B[K,N] (+ bias[N]), row-major.
// OutT = float (plain store) or unsigned short (bf16 store).
// M%128==0, N%64==0, K%16==0. 256 threads, 8x4 microtile.
// ---------------------------------------------------------------------------
template <int BM, int BN, int BK, typename OutT>
__global__ __launch_bounds__(256)
void gemm_f32(const float* __restrict__ A, const float* __restrict__ B,
              OutT* __restrict__ C, const float* __restrict__ bias,
              int M, int N, int K) {
    __shared__ float As[BK][BM + 4];  // transposed store, +4 pad
    __shared__ float Bs[BK][BN];

    const int t    = threadIdx.x;
    const int brow = blockIdx.x * BM;
    const int bcol = blockIdx.y * BN;

    const int tm = (t / 16) * 8;
    const int tn = (t % 16) * 4;

    const int ar = t / 4;
    const int ac = (t % 4) * 4;
    const int br = t / 16;
    const int bc = (t % 16) * 4;

    float acc[8][4];
#pragma unroll
    for (int i = 0; i < 8; ++i)
#pragma unroll
        for (int j = 0; j < 4; ++j) acc[i][j] = 0.f;

    const int ktiles = K / BK;
    for (int kt = 0; kt < ktiles; ++kt) {
        const int k0 = kt * BK;
        const float4 a0 = *(const float4*)&A[(size_t)(brow + ar) * K + k0 + ac];
        const float4 a1 = *(const float4*)&A[(size_t)(brow + ar + 64) * K + k0 + ac];
        const float4 b0 = *(const float4*)&B[(size_t)(k0 + br) * N + bcol + bc];

        __syncthreads();
        As[ac + 0][ar] = a0.x;  As[ac + 1][ar] = a0.y;
        As[ac + 2][ar] = a0.z;  As[ac + 3][ar] = a0.w;
        As[ac + 0][ar + 64] = a1.x;  As[ac + 1][ar + 64] = a1.y;
        As[ac + 2][ar + 64] = a1.z;  As[ac + 3][ar + 64] = a1.w;
        *(float4*)&Bs[br][bc] = b0;
        __syncthreads();

#pragma unroll
        for (int kk = 0; kk < BK; ++kk) {
            const float4 av0 = *(const float4*)&As[kk][tm];
            const float4 av1 = *(const float4*)&As[kk][tm + 4];
            const float4 bv  = *(const float4*)&Bs[kk][tn];
            const float a[8] = {av0.x, av0.y, av0.z, av0.w,
                                av1.x, av1.y, av1.z, av1.w};
            const float b[4] = {bv.x, bv.y, bv.z, bv.w};
#pragma unroll
            for (int i = 0; i < 8; ++i)
#pragma unroll
                for (int j = 0; j < 4; ++j)
                    acc[i][j] = fmaf(a[i], b[j], acc[i][j]);
        }
    }

    float bia[4] = {0.f, 0.f, 0.f, 0.f};
    if (bias) {
#pragma unroll
        for (int j = 0; j < 4; ++j) bia[j] = bias[bcol + tn + j];
    }

#pragma unroll
    for (int i = 0; i < 8; ++i) {
        float vj[4];
#pragma unroll
        for (int j = 0; j < 4; ++j) vj[j] = acc[i][j] + bia[j];
        if constexpr (sizeof(OutT) == 4) {
            float4 v = make_float4(vj[0], vj[1], vj[2], vj[3]);
            *(float4*)&C[(size_t)(brow + tm + i) * N + bcol + tn] = v;
        } else {
            ushort4 v;
            v.x = f2bf(vj[0]); v.y = f2bf(vj[1]);
            v.z = f2bf(vj[2]); v.w = f2bf(vj[3]);
            *(ushort4*)&C[(size_t)(brow + tm + i) * N + bcol + tn] = v;
        }
    }
}

// ---------------------------------------------------------------------------
// w_ih [192,64] -> wT [64,192]
// ---------------------------------------------------------------------------
__global__ void transpose_wih(const float* __restrict__ w, float* __restrict__ wT) {
    const int i = blockIdx.x * blockDim.x + threadIdx.x;
    if (i < GATES * PROJ) {
        const int g = i / PROJ, p = i % PROJ;
        wT[p * GATES + g] = w[i];
    }
}

// ---------------------------------------------------------------------------
// GRU scan, one wave per chain, zero barriers.
// Lane p owns gate rows {p, 64+p, 128+p} of w_hh in VGPRs (192 regs).
// Per step: h broadcast via LDS (1 ds_write + 16 uniform ds_read_b128),
// 96 v_pk_fma_f32, in-lane sigmoid/tanh. ig precomputed (bf16), prefetched
// 4 steps deep. ys written f32 (never waited on).
// ---------------------------------------------------------------------------
__global__ __launch_bounds__(64, 1)
void gru_scan2(const float* __restrict__ w_hh, const float* __restrict__ b_n,
               const unsigned short* __restrict__ ig, float* __restrict__ ys) {
    const int c = blockIdx.x;   // chain
    const int p = threadIdx.x;  // output index 0..63

    __shared__ float hl[PROJ];

    f2 wr[32], wz[32], wn[32];
    {
        const float4* r4 = (const float4*)&w_hh[(size_t)(0 * PROJ + p) * PROJ];
        const float4* z4 = (const float4*)&w_hh[(size_t)(1 * PROJ + p) * PROJ];
        const float4* n4 = (const float4*)&w_hh[(size_t)(2 * PROJ + p) * PROJ];
#pragma unroll
        for (int q = 0; q < 16; ++q) {
            const float4 a = r4[q]; wr[2*q] = f2{a.x, a.y}; wr[2*q+1] = f2{a.z, a.w};
            const float4 b = z4[q]; wz[2*q] = f2{b.x, b.y}; wz[2*q+1] = f2{b.z, b.w};
            const float d = 0.f; (void)d;
            const float4 e = n4[q]; wn[2*q] = f2{e.x, e.y}; wn[2*q+1] = f2{e.z, e.w};
        }
    }
    const float bn = b_n[p];

    hl[p] = 0.f;
    __syncthreads();  // once, before the loop
    float hreg = 0.f;

    const size_t STRIDE = (size_t)CHAINS * GATES;       // ushorts per step
    const unsigned short* igc = ig + (size_t)c * GATES;

    // 4-deep prefetch ring (statically indexed under unroll)
    unsigned short pr[4], pz[4], pn[4];
#pragma unroll
    for (int k = 0; k < 4; ++k) {
        const unsigned short* g = igc + (size_t)k * STRIDE;
        pr[k] = g[p]; pz[k] = g[PROJ + p]; pn[k] = g[2 * PROJ + p];
    }

    for (int sb = 0; sb < SEQ; sb += 4) {
#pragma unroll
        for (int u = 0; u < 4; ++u) {
            const int s = sb + u;
            const float igr = bf2f(pr[u]);
            const float igz = bf2f(pz[u]);
            const float ign = bf2f(pn[u]);
            {   // refill ring slot with step s+4
                int sn = s + 4; if (sn > SEQ - 1) sn = SEQ - 1;
                const unsigned short* g = igc + (size_t)sn * STRIDE;
                pr[u] = g[p]; pz[u] = g[PROJ + p]; pn[u] = g[2 * PROJ + p];
            }

            // hg = W_hh(3 rows) . h   — h broadcast from LDS (uniform reads)
            const float4* h4 = (const float4*)hl;
            f2 ar = {0.f, 0.f}, az = {0.f, 0.f}, an = {0.f, 0.f};
#pragma unroll
            for (int q = 0; q < 16; ++q) {
                const float4 hv = h4[q];
                const f2 h01 = {hv.x, hv.y};
                const f2 h23 = {hv.z, hv.w};
                PKFMA(ar, h01, wr[2*q]);
                PKFMA(az, h01, wz[2*q]);
                PKFMA(an, h01, wn[2*q]);
                PKFMA(ar, h23, wr[2*q+1]);
                PKFMA(az, h23, wz[2*q+1]);
                PKFMA(an, h23, wn[2*q+1]);
            }
            const float hgr = ar.x + ar.y;
            const float hgz = az.x + az.y;
            const float hgn = an.x + an.y;

            // r,z,n all in-lane: sigmoid/tanh via v_exp + v_rcp
            const float r = __builtin_amdgcn_rcpf(1.f + __expf(-(igr + hgr)));
            const float z = __builtin_amdgcn_rcpf(1.f + __expf(-(igz + hgz)));
            const float y2 = ign + r * (hgn + bn);
            const float t  = __expf(2.f * y2);                       // tanh(y2)
            const float nn = 1.f - 2.f * __builtin_amdgcn_rcpf(1.f + t);
            const float hnew = nn + z * (hreg - nn);
            hreg = hnew;

            hl[p] = hnew;  // own-wave LDS copy; same-wave DS ordering, no barrier
            ys[((size_t)s * CHAINS + c) * PROJ + p] = hnew;
        }
    }
}

// ---------------------------------------------------------------------------
extern "C" void kernel_launch(void* const* d_in, const int* in_sizes, int n_in,
                              void* d_out, int out_size, void* d_ws, size_t ws_size,
                              hipStream_t stream) {
    const float* x     = (const float*)d_in[0];  // [S,B,E]
    const float* w_in  = (const float*)d_in[1];  // [E,H,P] -> [1024,512]
    const float* w_ih  = (const float*)d_in[2];  // [192,64]
    const float* w_hh  = (const float*)d_in[3];  // [192,64]
    const float* b_ih  = (const float*)d_in[4];  // [192]
    const float* b_n   = (const float*)d_in[5];  // [64]
    const float* w_out = (const float*)d_in[6];  // [H,P,E] -> [512,1024]
    float* out = (float*)d_out;                  // [S,B,E]

    // ws layout: xp (f32, reused as ys) | ig (bf16) | w_ihT (f32)
    const size_t xp_bytes = (size_t)SEQ * CHAINS * PROJ * 4;    // 33.55 MB
    const size_t ig_bytes = (size_t)SEQ * CHAINS * GATES * 2;   // 50.33 MB
    float*          xp = (float*)d_ws;
    unsigned short* ig = (unsigned short*)((char*)d_ws + xp_bytes);
    float*          wT = (float*)((char*)d_ws + xp_bytes + ig_bytes);

    const int M = SEQ * BATCH;  // 16384

    // 0) w_ihT = transpose(w_ih)
    transpose_wih<<<(GATES * PROJ + 255) / 256, 256, 0, stream>>>(w_ih, wT);

    // 1) xp = x @ w_in   [16384,1024]x[1024,512]
    dim3 g1(M / 128, (HEADS * PROJ) / 64);
    gemm_f32<128, 64, 16, float><<<g1, 256, 0, stream>>>(
        x, w_in, xp, nullptr, M, HEADS * PROJ, EMB);

    // 2) ig = xp @ w_ihT + b_ih   [131072,64]x[64,192], bf16 out
    dim3 g2((SEQ * CHAINS) / 128, GATES / 64);
    gemm_f32<128, 64, 16, unsigned short><<<g2, 256, 0, stream>>>(
        xp, wT, ig, b_ih, SEQ * CHAINS, GATES, PROJ);

    // 3) GRU scan (ys overwrites xp region)
    gru_scan2<<<CHAINS, 64, 0, stream>>>(w_hh, b_n, ig, xp);

    // 4) out = ys @ w_out   [16384,512]x[512,1024]
    dim3 g4(M / 128, EMB / 64);
    gemm_f32<128, 64, 16, float><<<g4, 256, 0, stream>>>(
        xp, w_out, out, nullptr, M, EMB, HEADS * PROJ);
}

// Round 3
// 1370.831 us; speedup vs baseline: 1.5132x; 1.1747x over previous
//
#include <hip/hip_runtime.h>
#include <math.h>

#define SEQ    2048
#define BATCH  8
#define EMB    1024
#define HEADS  8
#define PROJ   64
#define CHAINS 64            // BATCH*HEADS
#define GATES  192           // 3*PROJ

typedef float f2  __attribute__((ext_vector_type(2)));
typedef float f4  __attribute__((ext_vector_type(4)));
typedef short s8v __attribute__((ext_vector_type(8)));

// packed f32 FMA: acc.xy += a.xy * b.xy
#define PKFMA(acc, a, b) asm("v_pk_fma_f32 %0, %1, %2, %0" : "+v"(acc) : "v"(a), "v"(b))

static __device__ __forceinline__ float bf2f(unsigned short u) {
    union { unsigned int i; float f; } c; c.i = ((unsigned int)u) << 16; return c.f;
}
static __device__ __forceinline__ unsigned short f2bf(float f) {
    union { float f; unsigned int i; } c; c.f = f;
    unsigned int u = c.i;
    u += 0x7fffu + ((u >> 16) & 1u);   // round-to-nearest-even
    return (unsigned short)(u >> 16);
}

// ---------------------------------------------------------------------------
// f32 [R][C] -> bf16 out [C][R]   (32x32 LDS tile, both sides coalesced)
// R, C multiples of 32. block = 256 (32x8).
// ---------------------------------------------------------------------------
__global__ __launch_bounds__(256)
void transpose_to_bf16(const float* __restrict__ in, unsigned short* __restrict__ out,
                       int R, int C) {
    __shared__ float tile[32][33];
    const int tx = threadIdx.x & 31, ty = threadIdx.x >> 5;
    const int c0 = blockIdx.x * 32, r0 = blockIdx.y * 32;
#pragma unroll
    for (int i = 0; i < 4; ++i)
        tile[ty + i * 8][tx] = in[(size_t)(r0 + ty + i * 8) * C + c0 + tx];
    __syncthreads();
#pragma unroll
    for (int i = 0; i < 4; ++i)
        out[(size_t)(c0 + ty + i * 8) * R + r0 + tx] = f2bf(tile[tx][ty + i * 8]);
}

__global__ void convert_bf16(const float* __restrict__ in, unsigned short* __restrict__ out, int n) {
    const int i = blockIdx.x * blockDim.x + threadIdx.x;
    if (i < n) out[i] = f2bf(in[i]);
}

// ---------------------------------------------------------------------------
// bf16 MFMA GEMM:  C[M][N] = A[M][K] * BT[N][K]^T  (+ bias[N])
//   A: f32 (converted in staging) if A_F32, else bf16.  BT: bf16 [N][K].
//   OutT: float or unsigned short (bf16).
// Tiles: BM x BN, BK=64; waves of 64x64 via 4x4 mfma_f32_16x16x32_bf16.
// Frag layout (gfx950): A row=lane&15, k=(lane>>4)*8+j; B col=lane&15, same k;
// D col=lane&15, row=(lane>>4)*4+reg  [verified m89/m91].
// ---------------------------------------------------------------------------
template <int BM, int BN, int BK, bool A_F32, typename OutT, bool BIAS>
__global__ __launch_bounds__((BM / 64) * (BN / 64) * 64)
void gemm_mfma(const void* __restrict__ Ap, const unsigned short* __restrict__ BT,
               OutT* __restrict__ C, const float* __restrict__ bias,
               int M, int N, int K) {
    constexpr int NWN = BN / 64;
    constexpr int NW  = (BM / 64) * NWN;
    constexpr int NT  = NW * 64;
    constexpr int KP  = BK + 8;            // padded row (bf16 elems), 16B-aligned
    __shared__ unsigned short Al[BM * KP];
    __shared__ unsigned short Bl[BN * KP];

    const int t    = threadIdx.x, lane = t & 63, wid = t >> 6;
    const int wm   = (wid / NWN) * 64, wn = (wid % NWN) * 64;
    const int bm   = blockIdx.x * BM, bn = blockIdx.y * BN;
    const int fr   = lane & 15;   // frag row (A) / col (B,D)
    const int fq   = lane >> 4;   // k sub-block / D row group

    f4 acc[4][4];
#pragma unroll
    for (int m = 0; m < 4; ++m)
#pragma unroll
        for (int n = 0; n < 4; ++n) acc[m][n] = f4{0.f, 0.f, 0.f, 0.f};

    const int nkt = K / BK;
    for (int kt = 0; kt < nkt; ++kt) {
        const int k0 = kt * BK;
        __syncthreads();   // previous tile consumed
        // ---- stage A (BM x BK) ----
        constexpr int CHA = (BM * BK / 8) / NT;
#pragma unroll
        for (int i = 0; i < CHA; ++i) {
            const int ci = t + i * NT;
            const int r = ci / (BK / 8), cc = (ci % (BK / 8)) * 8;
            if constexpr (A_F32) {
                const float* A = (const float*)Ap;
                const float4 u0 = *(const float4*)&A[(size_t)(bm + r) * K + k0 + cc];
                const float4 u1 = *(const float4*)&A[(size_t)(bm + r) * K + k0 + cc + 4];
                s8v w;
                w[0] = (short)f2bf(u0.x); w[1] = (short)f2bf(u0.y);
                w[2] = (short)f2bf(u0.z); w[3] = (short)f2bf(u0.w);
                w[4] = (short)f2bf(u1.x); w[5] = (short)f2bf(u1.y);
                w[6] = (short)f2bf(u1.z); w[7] = (short)f2bf(u1.w);
                *(s8v*)&Al[r * KP + cc] = w;
            } else {
                const unsigned short* A = (const unsigned short*)Ap;
                *(s8v*)&Al[r * KP + cc] = *(const s8v*)&A[(size_t)(bm + r) * K + k0 + cc];
            }
        }
        // ---- stage B (BN x BK) from BT[N][K] ----
        constexpr int CHB = (BN * BK / 8) / NT;
#pragma unroll
        for (int i = 0; i < CHB; ++i) {
            const int ci = t + i * NT;
            const int r = ci / (BK / 8), cc = (ci % (BK / 8)) * 8;
            *(s8v*)&Bl[r * KP + cc] = *(const s8v*)&BT[(size_t)(bn + r) * K + k0 + cc];
        }
        __syncthreads();   // tile staged
        // ---- compute ----
#pragma unroll
        for (int ks = 0; ks < BK / 32; ++ks) {
            s8v av[4], bv[4];
#pragma unroll
            for (int m = 0; m < 4; ++m)
                av[m] = *(const s8v*)&Al[(wm + m * 16 + fr) * KP + ks * 32 + fq * 8];
#pragma unroll
            for (int n = 0; n < 4; ++n)
                bv[n] = *(const s8v*)&Bl[(wn + n * 16 + fr) * KP + ks * 32 + fq * 8];
#pragma unroll
            for (int m = 0; m < 4; ++m)
#pragma unroll
                for (int n = 0; n < 4; ++n)
                    acc[m][n] = __builtin_amdgcn_mfma_f32_16x16x32_bf16(
                        av[m], bv[n], acc[m][n], 0, 0, 0);
        }
    }

    // ---- epilogue ----
#pragma unroll
    for (int n = 0; n < 4; ++n) {
        const int col = bn + wn + n * 16 + fr;
        const float bv = BIAS ? bias[col] : 0.f;
#pragma unroll
        for (int m = 0; m < 4; ++m) {
            const int row0 = bm + wm + m * 16 + fq * 4;
#pragma unroll
            for (int j = 0; j < 4; ++j) {
                const float val = acc[m][n][j] + bv;
                if constexpr (sizeof(OutT) == 4)
                    C[(size_t)(row0 + j) * N + col] = val;
                else
                    C[(size_t)(row0 + j) * N + col] = f2bf(val);
            }
        }
    }
}

// ---------------------------------------------------------------------------
// GRU scan, one wave per chain, zero barriers (same-wave LDS ordering).
// 4 accumulators per gate (dep spacing 12 insts). ig bf16 ring-prefetched
// 4 deep; ys written bf16 (feeds the MFMA output GEMM directly).
// ---------------------------------------------------------------------------
__global__ __launch_bounds__(64, 1)
void gru_scan3(const float* __restrict__ w_hh, const float* __restrict__ b_n,
               const unsigned short* __restrict__ ig, unsigned short* __restrict__ ys) {
    const int c = blockIdx.x;   // chain
    const int p = threadIdx.x;  // output index 0..63

    __shared__ float hl[PROJ];

    f2 wr[32], wz[32], wn[32];
    {
        const float4* r4 = (const float4*)&w_hh[(size_t)(0 * PROJ + p) * PROJ];
        const float4* z4 = (const float4*)&w_hh[(size_t)(1 * PROJ + p) * PROJ];
        const float4* n4 = (const float4*)&w_hh[(size_t)(2 * PROJ + p) * PROJ];
#pragma unroll
        for (int q = 0; q < 16; ++q) {
            const float4 a = r4[q]; wr[2*q] = f2{a.x, a.y}; wr[2*q+1] = f2{a.z, a.w};
            const float4 b = z4[q]; wz[2*q] = f2{b.x, b.y}; wz[2*q+1] = f2{b.z, b.w};
            const float4 e = n4[q]; wn[2*q] = f2{e.x, e.y}; wn[2*q+1] = f2{e.z, e.w};
        }
    }
    const float bn = b_n[p];

    hl[p] = 0.f;
    __syncthreads();  // once
    float hreg = 0.f;

    const size_t STRIDE = (size_t)CHAINS * GATES;
    const unsigned short* igc = ig + (size_t)c * GATES + p;

    unsigned short pr[4], pz[4], pn[4];
#pragma unroll
    for (int k = 0; k < 4; ++k) {
        const unsigned short* g = igc + (size_t)k * STRIDE;
        pr[k] = g[0]; pz[k] = g[PROJ]; pn[k] = g[2 * PROJ];
    }

    for (int sb = 0; sb < SEQ; sb += 4) {
#pragma unroll
        for (int u = 0; u < 4; ++u) {
            const int s = sb + u;
            const float igr = bf2f(pr[u]);
            const float igz = bf2f(pz[u]);
            const float ign = bf2f(pn[u]);
            {   // refill ring slot (consumed 4 steps later) — fills LDS shadow
                int sn = s + 4; if (sn > SEQ - 1) sn = SEQ - 1;
                const unsigned short* g = igc + (size_t)sn * STRIDE;
                pr[u] = g[0]; pz[u] = g[PROJ]; pn[u] = g[2 * PROJ];
            }

            // hg = W_hh(3 rows) . h  — h broadcast from LDS, 4 accums/gate
            const float4* h4 = (const float4*)hl;
            f2 ar[4], az[4], an[4];
#pragma unroll
            for (int k = 0; k < 4; ++k) { ar[k] = f2{0.f,0.f}; az[k] = f2{0.f,0.f}; an[k] = f2{0.f,0.f}; }
#pragma unroll
            for (int q = 0; q < 16; ++q) {
                const float4 hv = h4[q];
                const f2 h01 = {hv.x, hv.y};
                const f2 h23 = {hv.z, hv.w};
                const int i0 = (2 * q) & 3, i1 = (2 * q + 1) & 3;
                PKFMA(ar[i0], h01, wr[2*q]);
                PKFMA(az[i0], h01, wz[2*q]);
                PKFMA(an[i0], h01, wn[2*q]);
                PKFMA(ar[i1], h23, wr[2*q+1]);
                PKFMA(az[i1], h23, wz[2*q+1]);
                PKFMA(an[i1], h23, wn[2*q+1]);
            }
            const f2 rrv = (ar[0] + ar[1]) + (ar[2] + ar[3]);
            const f2 zzv = (az[0] + az[1]) + (az[2] + az[3]);
            const f2 nnv = (an[0] + an[1]) + (an[2] + an[3]);
            const float hgr = rrv.x + rrv.y;
            const float hgz = zzv.x + zzv.y;
            const float hgn = nnv.x + nnv.y;

            const float r = __builtin_amdgcn_rcpf(1.f + __expf(-(igr + hgr)));
            const float z = __builtin_amdgcn_rcpf(1.f + __expf(-(igz + hgz)));
            const float y  = ign + r * (hgn + bn);
            const float e2 = __expf(2.f * y);                      // tanh(y)
            const float nn = 1.f - 2.f * __builtin_amdgcn_rcpf(1.f + e2);
            const float hnew = nn + z * (hreg - nn);
            hreg = hnew;

            hl[p] = hnew;  // same-wave DS ordering; no barrier
            ys[((size_t)s * CHAINS + c) * PROJ + p] = f2bf(hnew);
        }
    }
}

// ---------------------------------------------------------------------------
extern "C" void kernel_launch(void* const* d_in, const int* in_sizes, int n_in,
                              void* d_out, int out_size, void* d_ws, size_t ws_size,
                              hipStream_t stream) {
    const float* x     = (const float*)d_in[0];  // [S,B,E]
    const float* w_in  = (const float*)d_in[1];  // [E=1024, H*P=512]
    const float* w_ih  = (const float*)d_in[2];  // [192,64]  (== BT layout [N][K])
    const float* w_hh  = (const float*)d_in[3];  // [192,64]
    const float* b_ih  = (const float*)d_in[4];  // [192]
    const float* b_n   = (const float*)d_in[5];  // [64]
    const float* w_out = (const float*)d_in[6];  // [H*P=512, E=1024]
    float* out = (float*)d_out;                  // [S,B,E] f32

    // ws layout (bytes):
    //   [0)              xp_bf / ys (bf16)  16.78 MB   (xp dead after ig GEMM)
    //   [16.78M)         ig (bf16)          50.33 MB
    //   [67.11M)         w_inT bf16 [512][1024]  1.05 MB
    //   [68.16M)         w_outT bf16 [1024][512] 1.05 MB
    //   [69.21M)         w_ih_bf bf16 [192][64]  24.6 KB     total ~69.2 MB
    char* ws = (char*)d_ws;
    unsigned short* xp_bf  = (unsigned short*)(ws);
    unsigned short* ysb    = (unsigned short*)(ws);                       // reuse
    unsigned short* ig     = (unsigned short*)(ws + (size_t)16777216 + 4194304);  // 20.97M? no:
    // (compute offsets explicitly)
    const size_t xp_bytes  = (size_t)SEQ * CHAINS * PROJ * 2;      // 16,777,216
    const size_t ig_bytes  = (size_t)SEQ * CHAINS * GATES * 2;     // 50,331,648
    ig = (unsigned short*)(ws + xp_bytes);
    unsigned short* w_inT  = (unsigned short*)(ws + xp_bytes + ig_bytes);
    unsigned short* w_outT = w_inT + (size_t)512 * 1024;
    unsigned short* w_ihb  = w_outT + (size_t)1024 * 512;

    // 0) weight preprocessing
    transpose_to_bf16<<<dim3(512 / 32, 1024 / 32), 256, 0, stream>>>(w_in, w_inT, 1024, 512);
    transpose_to_bf16<<<dim3(1024 / 32, 512 / 32), 256, 0, stream>>>(w_out, w_outT, 512, 1024);
    convert_bf16<<<(GATES * PROJ + 255) / 256, 256, 0, stream>>>(w_ih, w_ihb, GATES * PROJ);

    // 1) xp = x @ w_in      [16384 x 512], K=1024, A=f32 x, out bf16
    gemm_mfma<128, 128, 64, true, unsigned short, false>
        <<<dim3(16384 / 128, 512 / 128), 256, 0, stream>>>(
            x, w_inT, xp_bf, nullptr, 16384, 512, 1024);

    // 2) ig = xp @ w_ih^T + b_ih   [131072 x 192], K=64, out bf16
    gemm_mfma<128, 64, 64, false, unsigned short, true>
        <<<dim3(131072 / 128, 192 / 64), 128, 0, stream>>>(
            xp_bf, w_ihb, ig, b_ih, 131072, 192, 64);

    // 3) GRU scan (ys bf16 overwrites xp region)
    gru_scan3<<<CHAINS, 64, 0, stream>>>(w_hh, b_n, ig, ysb);

    // 4) out = ys @ w_out   [16384 x 1024], K=512, out f32
    gemm_mfma<128, 128, 64, false, float, false>
        <<<dim3(16384 / 128, 1024 / 128), 256, 0, stream>>>(
            ysb, w_outT, out, nullptr, 16384, 1024, 512);
}

// Round 4
// 1167.892 us; speedup vs baseline: 1.7762x; 1.1738x over previous
//
#include <hip/hip_runtime.h>
#include <math.h>

#define SEQ    2048
#define BATCH  8
#define EMB    1024
#define HEADS  8
#define PROJ   64
#define CHAINS 64            // BATCH*HEADS
#define GATES  192           // 3*PROJ

typedef float f2  __attribute__((ext_vector_type(2)));
typedef float f4  __attribute__((ext_vector_type(4)));
typedef short s8v __attribute__((ext_vector_type(8)));

// packed f32 FMA: acc.xy += a.xy * b.xy
#define PKFMA(acc, a, b) asm("v_pk_fma_f32 %0, %1, %2, %0" : "+v"(acc) : "v"(a), "v"(b))

#define AS1(p) ((const __attribute__((address_space(1))) void*)(p))
#define AS3(p) ((__attribute__((address_space(3))) void*)(p))

static __device__ __forceinline__ float bf2f(unsigned short u) {
    union { unsigned int i; float f; } c; c.i = ((unsigned int)u) << 16; return c.f;
}
static __device__ __forceinline__ unsigned short f2bf(float f) {
    union { float f; unsigned int i; } c; c.f = f;
    unsigned int u = c.i;
    u += 0x7fffu + ((u >> 16) & 1u);   // round-to-nearest-even
    return (unsigned short)(u >> 16);
}

// ---------------------------------------------------------------------------
// f32 [R][C] -> bf16 out [C][R]   (32x32 LDS tile, both sides coalesced)
// ---------------------------------------------------------------------------
__global__ __launch_bounds__(256)
void transpose_to_bf16(const float* __restrict__ in, unsigned short* __restrict__ out,
                       int R, int C) {
    __shared__ float tile[32][33];
    const int tx = threadIdx.x & 31, ty = threadIdx.x >> 5;
    const int c0 = blockIdx.x * 32, r0 = blockIdx.y * 32;
#pragma unroll
    for (int i = 0; i < 4; ++i)
        tile[ty + i * 8][tx] = in[(size_t)(r0 + ty + i * 8) * C + c0 + tx];
    __syncthreads();
#pragma unroll
    for (int i = 0; i < 4; ++i)
        out[(size_t)(c0 + ty + i * 8) * R + r0 + tx] = f2bf(tile[tx][ty + i * 8]);
}

__global__ void convert_bf16(const float* __restrict__ in, unsigned short* __restrict__ out, int n) {
    const int i = blockIdx.x * blockDim.x + threadIdx.x;
    if (i < n) out[i] = f2bf(in[i]);
}

// ---------------------------------------------------------------------------
// bf16 MFMA GEMM:  C[M][N] = A[M][K] * BT[N][K]^T  (+ bias[N])
// PERM: output row m -> (m&63)*SEQ + (m>>6)   (ig relayout [s][c] -> [c][s])
// ---------------------------------------------------------------------------
template <int BM, int BN, int BK, bool A_F32, typename OutT, bool BIAS, bool PERM>
__global__ __launch_bounds__((BM / 64) * (BN / 64) * 64)
void gemm_mfma(const void* __restrict__ Ap, const unsigned short* __restrict__ BT,
               OutT* __restrict__ C, const float* __restrict__ bias,
               int M, int N, int K) {
    constexpr int NWN = BN / 64;
    constexpr int NW  = (BM / 64) * NWN;
    constexpr int NT  = NW * 64;
    constexpr int KP  = BK + 8;            // padded row (bf16 elems)
    __shared__ unsigned short Al[BM * KP];
    __shared__ unsigned short Bl[BN * KP];

    const int t    = threadIdx.x, lane = t & 63, wid = t >> 6;
    const int wm   = (wid / NWN) * 64, wn = (wid % NWN) * 64;
    const int bm   = blockIdx.x * BM, bn = blockIdx.y * BN;
    const int fr   = lane & 15;
    const int fq   = lane >> 4;

    f4 acc[4][4];
#pragma unroll
    for (int m = 0; m < 4; ++m)
#pragma unroll
        for (int n = 0; n < 4; ++n) acc[m][n] = f4{0.f, 0.f, 0.f, 0.f};

    const int nkt = K / BK;
    for (int kt = 0; kt < nkt; ++kt) {
        const int k0 = kt * BK;
        __syncthreads();
        constexpr int CHA = (BM * BK / 8) / NT;
#pragma unroll
        for (int i = 0; i < CHA; ++i) {
            const int ci = t + i * NT;
            const int r = ci / (BK / 8), cc = (ci % (BK / 8)) * 8;
            if constexpr (A_F32) {
                const float* A = (const float*)Ap;
                const float4 u0 = *(const float4*)&A[(size_t)(bm + r) * K + k0 + cc];
                const float4 u1 = *(const float4*)&A[(size_t)(bm + r) * K + k0 + cc + 4];
                s8v w;
                w[0] = (short)f2bf(u0.x); w[1] = (short)f2bf(u0.y);
                w[2] = (short)f2bf(u0.z); w[3] = (short)f2bf(u0.w);
                w[4] = (short)f2bf(u1.x); w[5] = (short)f2bf(u1.y);
                w[6] = (short)f2bf(u1.z); w[7] = (short)f2bf(u1.w);
                *(s8v*)&Al[r * KP + cc] = w;
            } else {
                const unsigned short* A = (const unsigned short*)Ap;
                *(s8v*)&Al[r * KP + cc] = *(const s8v*)&A[(size_t)(bm + r) * K + k0 + cc];
            }
        }
        constexpr int CHB = (BN * BK / 8) / NT;
#pragma unroll
        for (int i = 0; i < CHB; ++i) {
            const int ci = t + i * NT;
            const int r = ci / (BK / 8), cc = (ci % (BK / 8)) * 8;
            *(s8v*)&Bl[r * KP + cc] = *(const s8v*)&BT[(size_t)(bn + r) * K + k0 + cc];
        }
        __syncthreads();
#pragma unroll
        for (int ks = 0; ks < BK / 32; ++ks) {
            s8v av[4], bv[4];
#pragma unroll
            for (int m = 0; m < 4; ++m)
                av[m] = *(const s8v*)&Al[(wm + m * 16 + fr) * KP + ks * 32 + fq * 8];
#pragma unroll
            for (int n = 0; n < 4; ++n)
                bv[n] = *(const s8v*)&Bl[(wn + n * 16 + fr) * KP + ks * 32 + fq * 8];
#pragma unroll
            for (int m = 0; m < 4; ++m)
#pragma unroll
                for (int n = 0; n < 4; ++n)
                    acc[m][n] = __builtin_amdgcn_mfma_f32_16x16x32_bf16(
                        av[m], bv[n], acc[m][n], 0, 0, 0);
        }
    }

#pragma unroll
    for (int n = 0; n < 4; ++n) {
        const int col = bn + wn + n * 16 + fr;
        const float bv = BIAS ? bias[col] : 0.f;
#pragma unroll
        for (int m = 0; m < 4; ++m) {
            const int row0 = bm + wm + m * 16 + fq * 4;
#pragma unroll
            for (int j = 0; j < 4; ++j) {
                const float val = acc[m][n][j] + bv;
                const int row = row0 + j;
                const size_t orow = PERM ? ((size_t)(row & 63) * SEQ + (row >> 6))
                                         : (size_t)row;
                if constexpr (sizeof(OutT) == 4)
                    C[orow * N + col] = val;
                else
                    C[orow * N + col] = f2bf(val);
            }
        }
    }
}

// ---------------------------------------------------------------------------
// GRU scan v4. One wave per chain, zero barriers.
// ig is [chain][SEQ][GATES] bf16: per-chain contiguous stream, staged into a
// 2x6KB LDS ring via global_load_lds (16 steps / 6 loads per buffer, issued
// 16 steps = ~8K cycles ahead). One vmcnt(0) per 16 steps.
// Lane p owns w_hh rows {p, 64+p, 128+p} in 192 VGPRs; h broadcast via LDS.
// ---------------------------------------------------------------------------
__global__ __launch_bounds__(64, 1)
void gru_scan4(const float* __restrict__ w_hh, const float* __restrict__ b_n,
               const unsigned short* __restrict__ ig, unsigned short* __restrict__ ys) {
    const int c = blockIdx.x;   // chain
    const int p = threadIdx.x;  // output index 0..63

    __shared__ float hl[PROJ];
    __shared__ uint4 igl[2][384];   // 2 buffers x 6144 B (16 steps x 384 B)

    f2 wr[32], wz[32], wn[32];
    {
        const float4* r4 = (const float4*)&w_hh[(size_t)(0 * PROJ + p) * PROJ];
        const float4* z4 = (const float4*)&w_hh[(size_t)(1 * PROJ + p) * PROJ];
        const float4* n4 = (const float4*)&w_hh[(size_t)(2 * PROJ + p) * PROJ];
#pragma unroll
        for (int q = 0; q < 16; ++q) {
            const float4 a = r4[q]; wr[2*q] = f2{a.x, a.y}; wr[2*q+1] = f2{a.z, a.w};
            const float4 b = z4[q]; wz[2*q] = f2{b.x, b.y}; wz[2*q+1] = f2{b.z, b.w};
            const float4 e = n4[q]; wn[2*q] = f2{e.x, e.y}; wn[2*q+1] = f2{e.z, e.w};
        }
    }
    const float bn = b_n[p];

    hl[p] = 0.f;      // same-wave DS ordering; no barrier needed (1 wave)
    float hreg = 0.f;

    const char* gbase = (const char*)(ig + (size_t)c * SEQ * GATES);

    // prologue: stage steps 0..15 into buffer 0
#pragma unroll
    for (int i = 0; i < 6; ++i)
        __builtin_amdgcn_global_load_lds(AS1(gbase + i * 1024 + p * 16),
                                         AS3((char*)&igl[0][0] + i * 1024), 16, 0, 0);

    for (int sb = 0; sb < SEQ; sb += 16) {
        const int buf = (sb >> 4) & 1;
        asm volatile("s_waitcnt vmcnt(0)" ::: "memory");
        __builtin_amdgcn_sched_barrier(0);
        {   // prefetch steps sb+16..sb+31 into the other buffer
            const int nb = (sb + 16 < SEQ) ? sb + 16 : sb;
            const char* src = gbase + (size_t)nb * (GATES * 2);
            char* dst = (char*)&igl[buf ^ 1][0];
#pragma unroll
            for (int i = 0; i < 6; ++i)
                __builtin_amdgcn_global_load_lds(AS1(src + i * 1024 + p * 16),
                                                 AS3(dst + i * 1024), 16, 0, 0);
        }
        __builtin_amdgcn_sched_barrier(0);

#pragma unroll 4
        for (int u = 0; u < 16; ++u) {
            const int s = sb + u;
            const unsigned short* igb = (const unsigned short*)&igl[buf][0] + u * GATES;
            const float igr = bf2f(igb[p]);
            const float igz = bf2f(igb[PROJ + p]);
            const float ign = bf2f(igb[2 * PROJ + p]);

            // hg = W_hh(3 rows) . h  — h broadcast from LDS (uniform b128 reads)
            const float4* h4 = (const float4*)hl;
            f2 ar = {0.f, 0.f}, az = {0.f, 0.f}, an = {0.f, 0.f};
#pragma unroll
            for (int q = 0; q < 16; ++q) {
                const float4 hv = h4[q];
                const f2 h01 = {hv.x, hv.y};
                const f2 h23 = {hv.z, hv.w};
                PKFMA(ar, h01, wr[2*q]);
                PKFMA(az, h01, wz[2*q]);
                PKFMA(an, h01, wn[2*q]);
                PKFMA(ar, h23, wr[2*q+1]);
                PKFMA(az, h23, wz[2*q+1]);
                PKFMA(an, h23, wn[2*q+1]);
            }
            const float hgr = ar.x + ar.y;
            const float hgz = az.x + az.y;
            const float hgn = an.x + an.y;

            const float r = __builtin_amdgcn_rcpf(1.f + __expf(-(igr + hgr)));
            const float z = __builtin_amdgcn_rcpf(1.f + __expf(-(igz + hgz)));
            const float y  = ign + r * (hgn + bn);
            const float e2 = __expf(2.f * y);                      // tanh(y)
            const float nn = 1.f - 2.f * __builtin_amdgcn_rcpf(1.f + e2);
            const float hnew = nn + z * (hreg - nn);
            hreg = hnew;

            hl[p] = hnew;  // same-wave DS ordering; no barrier
            ys[((size_t)s * CHAINS + c) * PROJ + p] = f2bf(hnew);
        }
    }
}

// ---------------------------------------------------------------------------
extern "C" void kernel_launch(void* const* d_in, const int* in_sizes, int n_in,
                              void* d_out, int out_size, void* d_ws, size_t ws_size,
                              hipStream_t stream) {
    const float* x     = (const float*)d_in[0];  // [S,B,E]
    const float* w_in  = (const float*)d_in[1];  // [E=1024, H*P=512]
    const float* w_ih  = (const float*)d_in[2];  // [192,64]  (BT layout [N][K])
    const float* w_hh  = (const float*)d_in[3];  // [192,64]
    const float* b_ih  = (const float*)d_in[4];  // [192]
    const float* b_n   = (const float*)d_in[5];  // [64]
    const float* w_out = (const float*)d_in[6];  // [H*P=512, E=1024]
    float* out = (float*)d_out;                  // [S,B,E] f32

    char* ws = (char*)d_ws;
    const size_t xp_bytes  = (size_t)SEQ * CHAINS * PROJ * 2;      // 16,777,216
    const size_t ig_bytes  = (size_t)SEQ * CHAINS * GATES * 2;     // 50,331,648
    unsigned short* xp_bf  = (unsigned short*)(ws);
    unsigned short* ysb    = (unsigned short*)(ws);                // reuse
    unsigned short* ig     = (unsigned short*)(ws + xp_bytes);     // [c][s][g]
    unsigned short* w_inT  = (unsigned short*)(ws + xp_bytes + ig_bytes);
    unsigned short* w_outT = w_inT + (size_t)512 * 1024;
    unsigned short* w_ihb  = w_outT + (size_t)1024 * 512;

    // 0) weight preprocessing
    transpose_to_bf16<<<dim3(512 / 32, 1024 / 32), 256, 0, stream>>>(w_in, w_inT, 1024, 512);
    transpose_to_bf16<<<dim3(1024 / 32, 512 / 32), 256, 0, stream>>>(w_out, w_outT, 512, 1024);
    convert_bf16<<<(GATES * PROJ + 255) / 256, 256, 0, stream>>>(w_ih, w_ihb, GATES * PROJ);

    // 1) xp = x @ w_in      [16384 x 512], K=1024
    gemm_mfma<128, 128, 64, true, unsigned short, false, false>
        <<<dim3(16384 / 128, 512 / 128), 256, 0, stream>>>(
            x, w_inT, xp_bf, nullptr, 16384, 512, 1024);

    // 2) ig = xp @ w_ih^T + b_ih   [131072 x 192], K=64; output PERMUTED to [c][s][g]
    gemm_mfma<128, 64, 64, false, unsigned short, true, true>
        <<<dim3(131072 / 128, 192 / 64), 128, 0, stream>>>(
            xp_bf, w_ihb, ig, b_ih, 131072, 192, 64);

    // 3) GRU scan (ys bf16 overwrites xp region)
    gru_scan4<<<CHAINS, 64, 0, stream>>>(w_hh, b_n, ig, ysb);

    // 4) out = ys @ w_out   [16384 x 1024], K=512
    gemm_mfma<128, 128, 64, false, float, false, false>
        <<<dim3(16384 / 128, 1024 / 128), 256, 0, stream>>>(
            ysb, w_outT, out, nullptr, 16384, 1024, 512);
}

// Round 5
// 761.860 us; speedup vs baseline: 2.7228x; 1.5329x over previous
//
#include <hip/hip_runtime.h>
#include <math.h>

#define SEQ    2048
#define BATCH  8
#define EMB    1024
#define HEADS  8
#define PROJ   64
#define CHAINS 64            // BATCH*HEADS
#define GATES  192           // 3*PROJ

typedef float f4  __attribute__((ext_vector_type(4)));
typedef short s8v __attribute__((ext_vector_type(8)));
typedef _Float16 h2v __attribute__((ext_vector_type(2)));

#define AS1(p) ((const __attribute__((address_space(1))) void*)(p))
#define AS3(p) ((__attribute__((address_space(3))) void*)(p))

static __device__ __forceinline__ float bf2f(unsigned short u) {
    union { unsigned int i; float f; } c; c.i = ((unsigned int)u) << 16; return c.f;
}
static __device__ __forceinline__ unsigned short f2bf(float f) {
    union { float f; unsigned int i; } c; c.f = f;
    unsigned int u = c.i;
    u += 0x7fffu + ((u >> 16) & 1u);   // round-to-nearest-even
    return (unsigned short)(u >> 16);
}
// dot2: c += a.x*b.x + a.y*b.y   (f16 inputs, f32 accum)
static __device__ __forceinline__ float fdot2u(unsigned int a, unsigned int b, float c) {
    union { unsigned int u; h2v h; } ua, ub; ua.u = a; ub.u = b;
    return __builtin_amdgcn_fdot2(ua.h, ub.h, c, false);
}

// ---------------------------------------------------------------------------
// f32 [R][C] -> bf16 out [C][R]   (32x32 LDS tile, both sides coalesced)
// ---------------------------------------------------------------------------
__global__ __launch_bounds__(256)
void transpose_to_bf16(const float* __restrict__ in, unsigned short* __restrict__ out,
                       int R, int C) {
    __shared__ float tile[32][33];
    const int tx = threadIdx.x & 31, ty = threadIdx.x >> 5;
    const int c0 = blockIdx.x * 32, r0 = blockIdx.y * 32;
#pragma unroll
    for (int i = 0; i < 4; ++i)
        tile[ty + i * 8][tx] = in[(size_t)(r0 + ty + i * 8) * C + c0 + tx];
    __syncthreads();
#pragma unroll
    for (int i = 0; i < 4; ++i)
        out[(size_t)(c0 + ty + i * 8) * R + r0 + tx] = f2bf(tile[tx][ty + i * 8]);
}

__global__ void convert_bf16(const float* __restrict__ in, unsigned short* __restrict__ out, int n) {
    const int i = blockIdx.x * blockDim.x + threadIdx.x;
    if (i < n) out[i] = f2bf(in[i]);
}

__global__ void convert_f16(const float* __restrict__ in, unsigned short* __restrict__ out, int n) {
    const int i = blockIdx.x * blockDim.x + threadIdx.x;
    if (i < n) {
        union { _Float16 h; unsigned short u; } c;
        c.h = (_Float16)in[i];
        out[i] = c.u;
    }
}

// ---------------------------------------------------------------------------
// bf16 MFMA GEMM:  C[M][N] = A[M][K] * BT[N][K]^T  (+ bias[N])
// PERM: output row m -> (m&63)*SEQ + (m>>6)   (ig relayout [s][c] -> [c][s])
// ---------------------------------------------------------------------------
template <int BM, int BN, int BK, bool A_F32, typename OutT, bool BIAS, bool PERM>
__global__ __launch_bounds__((BM / 64) * (BN / 64) * 64)
void gemm_mfma(const void* __restrict__ Ap, const unsigned short* __restrict__ BT,
               OutT* __restrict__ C, const float* __restrict__ bias,
               int M, int N, int K) {
    constexpr int NWN = BN / 64;
    constexpr int NW  = (BM / 64) * NWN;
    constexpr int NT  = NW * 64;
    constexpr int KP  = BK + 8;            // padded row (bf16 elems)
    __shared__ unsigned short Al[BM * KP];
    __shared__ unsigned short Bl[BN * KP];

    const int t    = threadIdx.x, lane = t & 63, wid = t >> 6;
    const int wm   = (wid / NWN) * 64, wn = (wid % NWN) * 64;
    const int bm   = blockIdx.x * BM, bn = blockIdx.y * BN;
    const int fr   = lane & 15;
    const int fq   = lane >> 4;

    f4 acc[4][4];
#pragma unroll
    for (int m = 0; m < 4; ++m)
#pragma unroll
        for (int n = 0; n < 4; ++n) acc[m][n] = f4{0.f, 0.f, 0.f, 0.f};

    const int nkt = K / BK;
    for (int kt = 0; kt < nkt; ++kt) {
        const int k0 = kt * BK;
        __syncthreads();
        constexpr int CHA = (BM * BK / 8) / NT;
#pragma unroll
        for (int i = 0; i < CHA; ++i) {
            const int ci = t + i * NT;
            const int r = ci / (BK / 8), cc = (ci % (BK / 8)) * 8;
            if constexpr (A_F32) {
                const float* A = (const float*)Ap;
                const float4 u0 = *(const float4*)&A[(size_t)(bm + r) * K + k0 + cc];
                const float4 u1 = *(const float4*)&A[(size_t)(bm + r) * K + k0 + cc + 4];
                s8v w;
                w[0] = (short)f2bf(u0.x); w[1] = (short)f2bf(u0.y);
                w[2] = (short)f2bf(u0.z); w[3] = (short)f2bf(u0.w);
                w[4] = (short)f2bf(u1.x); w[5] = (short)f2bf(u1.y);
                w[6] = (short)f2bf(u1.z); w[7] = (short)f2bf(u1.w);
                *(s8v*)&Al[r * KP + cc] = w;
            } else {
                const unsigned short* A = (const unsigned short*)Ap;
                *(s8v*)&Al[r * KP + cc] = *(const s8v*)&A[(size_t)(bm + r) * K + k0 + cc];
            }
        }
        constexpr int CHB = (BN * BK / 8) / NT;
#pragma unroll
        for (int i = 0; i < CHB; ++i) {
            const int ci = t + i * NT;
            const int r = ci / (BK / 8), cc = (ci % (BK / 8)) * 8;
            *(s8v*)&Bl[r * KP + cc] = *(const s8v*)&BT[(size_t)(bn + r) * K + k0 + cc];
        }
        __syncthreads();
#pragma unroll
        for (int ks = 0; ks < BK / 32; ++ks) {
            s8v av[4], bv[4];
#pragma unroll
            for (int m = 0; m < 4; ++m)
                av[m] = *(const s8v*)&Al[(wm + m * 16 + fr) * KP + ks * 32 + fq * 8];
#pragma unroll
            for (int n = 0; n < 4; ++n)
                bv[n] = *(const s8v*)&Bl[(wn + n * 16 + fr) * KP + ks * 32 + fq * 8];
#pragma unroll
            for (int m = 0; m < 4; ++m)
#pragma unroll
                for (int n = 0; n < 4; ++n)
                    acc[m][n] = __builtin_amdgcn_mfma_f32_16x16x32_bf16(
                        av[m], bv[n], acc[m][n], 0, 0, 0);
        }
    }

#pragma unroll
    for (int n = 0; n < 4; ++n) {
        const int col = bn + wn + n * 16 + fr;
        const float bv = BIAS ? bias[col] : 0.f;
#pragma unroll
        for (int m = 0; m < 4; ++m) {
            const int row0 = bm + wm + m * 16 + fq * 4;
#pragma unroll
            for (int j = 0; j < 4; ++j) {
                const float val = acc[m][n][j] + bv;
                const int row = row0 + j;
                const size_t orow = PERM ? ((size_t)(row & 63) * SEQ + (row >> 6))
                                         : (size_t)row;
                if constexpr (sizeof(OutT) == 4)
                    C[orow * N + col] = val;
                else
                    C[orow * N + col] = f2bf(val);
            }
        }
    }
}

// ---------------------------------------------------------------------------
// GRU scan v5. One wave per chain, zero barriers.
// h kept in LDS as packed f16 (128 B): 1 ds_write_b16 + 8 ds_read_b128/step.
// Matvec via v_dot2_f32_f16 (96 ops, 4 accums/gate). ig staged via
// global_load_lds double-buffer (16 steps deep). h-reads for step s+1 issued
// right after the h-write of step s (same-wave DS ordering) so LDS latency
// overlaps the ys store / bookkeeping.
// ---------------------------------------------------------------------------
__global__ __launch_bounds__(64, 1)
void gru_scan5(const unsigned short* __restrict__ w_hh16, const float* __restrict__ b_n,
               const unsigned short* __restrict__ ig, unsigned short* __restrict__ ys) {
    const int c = blockIdx.x;   // chain
    const int p = threadIdx.x;  // output index 0..63

    __shared__ unsigned short hl16[PROJ];   // h as packed f16 pairs (128 B)
    __shared__ uint4 igl[2][384];           // 2 x 6144 B (16 steps x 384 B)

    // weights: rows {p, 64+p, 128+p} as 32 f16-pairs each (96 VGPRs total)
    unsigned int wru[32], wzu[32], wnu[32];
#pragma unroll
    for (int q = 0; q < 8; ++q) {
        const uint4 a = *(const uint4*)&w_hh16[(size_t)(0 * PROJ + p) * PROJ + q * 8];
        wru[4*q+0] = a.x; wru[4*q+1] = a.y; wru[4*q+2] = a.z; wru[4*q+3] = a.w;
        const uint4 b = *(const uint4*)&w_hh16[(size_t)(1 * PROJ + p) * PROJ + q * 8];
        wzu[4*q+0] = b.x; wzu[4*q+1] = b.y; wzu[4*q+2] = b.z; wzu[4*q+3] = b.w;
        const uint4 e = *(const uint4*)&w_hh16[(size_t)(2 * PROJ + p) * PROJ + q * 8];
        wnu[4*q+0] = e.x; wnu[4*q+1] = e.y; wnu[4*q+2] = e.z; wnu[4*q+3] = e.w;
    }
    const float bn = b_n[p];

    hl16[p] = 0;        // f16 zero; same-wave DS ordering, no barrier
    float hreg = 0.f;

    const char* gbase = (const char*)(ig + (size_t)c * SEQ * GATES);

    // prologue: stage steps 0..15 into buffer 0
#pragma unroll
    for (int i = 0; i < 6; ++i)
        __builtin_amdgcn_global_load_lds(AS1(gbase + i * 1024 + p * 16),
                                         AS3((char*)&igl[0][0] + i * 1024), 16, 0, 0);

    // initial h fragment (all zeros, but read through the real path)
    unsigned int hw[32];
#pragma unroll
    for (int q = 0; q < 8; ++q) {
        const uint4 v = ((const uint4*)hl16)[q];
        hw[4*q+0] = v.x; hw[4*q+1] = v.y; hw[4*q+2] = v.z; hw[4*q+3] = v.w;
    }

    for (int sb = 0; sb < SEQ; sb += 16) {
        const int buf = (sb >> 4) & 1;
        asm volatile("s_waitcnt vmcnt(0)" ::: "memory");
        __builtin_amdgcn_sched_barrier(0);
        {   // prefetch steps sb+16..sb+31 into the other buffer
            const int nb = (sb + 16 < SEQ) ? sb + 16 : sb;
            const char* src = gbase + (size_t)nb * (GATES * 2);
            char* dst = (char*)&igl[buf ^ 1][0];
#pragma unroll
            for (int i = 0; i < 6; ++i)
                __builtin_amdgcn_global_load_lds(AS1(src + i * 1024 + p * 16),
                                                 AS3(dst + i * 1024), 16, 0, 0);
        }
        __builtin_amdgcn_sched_barrier(0);

#pragma unroll 4
        for (int u = 0; u < 16; ++u) {
            const int s = sb + u;
            const unsigned short* igb = (const unsigned short*)&igl[buf][0] + u * GATES;
            // ig reads (LDS): consumed late (at sigmoid time)
            const unsigned short ur = igb[p];
            const unsigned short uz = igb[PROJ + p];
            const unsigned short un = igb[2 * PROJ + p];

            // hg = W_hh(3 rows) . h  — f16 dot2, 4 accumulators per gate
            float ar[4] = {0.f,0.f,0.f,0.f}, az[4] = {0.f,0.f,0.f,0.f}, an[4] = {0.f,0.f,0.f,0.f};
#pragma unroll
            for (int i = 0; i < 32; ++i) {
                const unsigned int h2 = hw[i];
                ar[i & 3] = fdot2u(h2, wru[i], ar[i & 3]);
                an[i & 3] = fdot2u(h2, wnu[i], an[i & 3]);
                az[i & 3] = fdot2u(h2, wzu[i], az[i & 3]);
            }
            const float hgr = (ar[0] + ar[1]) + (ar[2] + ar[3]);
            const float hgn = (an[0] + an[1]) + (an[2] + an[3]);
            const float hgz = (az[0] + az[1]) + (az[2] + az[3]);

            const float r = __builtin_amdgcn_rcpf(1.f + __expf(-(bf2f(ur) + hgr)));
            const float z = __builtin_amdgcn_rcpf(1.f + __expf(-(bf2f(uz) + hgz)));
            const float y  = bf2f(un) + r * (hgn + bn);
            const float e2 = __expf(2.f * y);                      // tanh(y)
            const float nn = 1.f - 2.f * __builtin_amdgcn_rcpf(1.f + e2);
            const float hnew = nn + z * (hreg - nn);
            hreg = hnew;

            // write h (f16), then immediately issue next step's h reads so the
            // LDS round-trip overlaps the ys store + loop bookkeeping
            union { _Float16 h; unsigned short u; } cv; cv.h = (_Float16)hnew;
            hl16[p] = cv.u;
#pragma unroll
            for (int q = 0; q < 8; ++q) {
                const uint4 v = ((const uint4*)hl16)[q];
                hw[4*q+0] = v.x; hw[4*q+1] = v.y; hw[4*q+2] = v.z; hw[4*q+3] = v.w;
            }
            ys[((size_t)s * CHAINS + c) * PROJ + p] = f2bf(hnew);
        }
    }
}

// ---------------------------------------------------------------------------
extern "C" void kernel_launch(void* const* d_in, const int* in_sizes, int n_in,
                              void* d_out, int out_size, void* d_ws, size_t ws_size,
                              hipStream_t stream) {
    const float* x     = (const float*)d_in[0];  // [S,B,E]
    const float* w_in  = (const float*)d_in[1];  // [E=1024, H*P=512]
    const float* w_ih  = (const float*)d_in[2];  // [192,64]  (BT layout [N][K])
    const float* w_hh  = (const float*)d_in[3];  // [192,64]
    const float* b_ih  = (const float*)d_in[4];  // [192]
    const float* b_n   = (const float*)d_in[5];  // [64]
    const float* w_out = (const float*)d_in[6];  // [H*P=512, E=1024]
    float* out = (float*)d_out;                  // [S,B,E] f32

    char* ws = (char*)d_ws;
    const size_t xp_bytes  = (size_t)SEQ * CHAINS * PROJ * 2;      // 16,777,216
    const size_t ig_bytes  = (size_t)SEQ * CHAINS * GATES * 2;     // 50,331,648
    unsigned short* xp_bf  = (unsigned short*)(ws);
    unsigned short* ysb    = (unsigned short*)(ws);                // reuse
    unsigned short* ig     = (unsigned short*)(ws + xp_bytes);     // [c][s][g]
    unsigned short* w_inT  = (unsigned short*)(ws + xp_bytes + ig_bytes);
    unsigned short* w_outT = w_inT + (size_t)512 * 1024;
    unsigned short* w_ihb  = w_outT + (size_t)1024 * 512;
    unsigned short* w_hh16 = w_ihb + (size_t)GATES * PROJ;

    // 0) weight preprocessing
    transpose_to_bf16<<<dim3(512 / 32, 1024 / 32), 256, 0, stream>>>(w_in, w_inT, 1024, 512);
    transpose_to_bf16<<<dim3(1024 / 32, 512 / 32), 256, 0, stream>>>(w_out, w_outT, 512, 1024);
    convert_bf16<<<(GATES * PROJ + 255) / 256, 256, 0, stream>>>(w_ih, w_ihb, GATES * PROJ);
    convert_f16<<<(GATES * PROJ + 255) / 256, 256, 0, stream>>>(w_hh, w_hh16, GATES * PROJ);

    // 1) xp = x @ w_in      [16384 x 512], K=1024
    gemm_mfma<128, 128, 64, true, unsigned short, false, false>
        <<<dim3(16384 / 128, 512 / 128), 256, 0, stream>>>(
            x, w_inT, xp_bf, nullptr, 16384, 512, 1024);

    // 2) ig = xp @ w_ih^T + b_ih   [131072 x 192], K=64; output PERMUTED to [c][s][g]
    gemm_mfma<128, 64, 64, false, unsigned short, true, true>
        <<<dim3(131072 / 128, 192 / 64), 128, 0, stream>>>(
            xp_bf, w_ihb, ig, b_ih, 131072, 192, 64);

    // 3) GRU scan (ys bf16 overwrites xp region)
    gru_scan5<<<CHAINS, 64, 0, stream>>>(w_hh16, b_n, ig, ysb);

    // 4) out = ys @ w_out   [16384 x 1024], K=512
    gemm_mfma<128, 128, 64, false, float, false, false>
        <<<dim3(16384 / 128, 1024 / 128), 256, 0, stream>>>(
            ysb, w_outT, out, nullptr, 16384, 1024, 512);
}